// Round 13
// baseline (168.885 us; speedup 1.0000x reference)
//
#include <hip/hip_runtime.h>

typedef __fp16 h2 __attribute__((ext_vector_type(2)));

constexpr int VIEWS = 360;
constexpr int IMGSZ = 512;
constexpr int WCHUNK = 32;   // w per block (32 w x 8 h-phases x 256 threads)
constexpr int KH = 64;       // h per LDS chunk
constexpr int NXF4 = 20;     // staged box width in 4-dword groups (80 texels)
constexpr int PITCH = 82;    // LDS row pitch; 82 mod 32 = 18, gcd=2 -> benign banks
constexpr int MAXNY = 75;    // max staged rows: sqrt(31^2+63^2)+5 <= 75
constexpr int PW = 712;      // padded width (dword positions per row)
constexpr int PH = 704;      // padded height
constexpr int PAD = 96;
// tile = 82*75 = 6150 dwords = 24600 B -> ~6 blocks/CU theoretical

// ---------- pad kernel: zero-padded, BATCH-PACKED f16 texels ---------------
__global__ __launch_bounds__(256) void pad_kernel(const float* __restrict__ x,
                                                  unsigned* __restrict__ padq) {
    constexpr int PW4 = PW / 4;
    constexpr int total = PH * PW4;
    int idx = blockIdx.x * 256 + threadIdx.x;
    if (idx >= total) return;
    int py = idx / PW4;
    int px4 = idx - py * PW4;
    int gx = px4 * 4 - PAD;                  // multiple of 4
    int gy = py - PAD;
    const float* img0 = x;
    const float* img1 = x + (size_t)IMGSZ * IMGSZ;
    float4 a = make_float4(0.f, 0.f, 0.f, 0.f);
    float4 bq = a;
    if ((unsigned)gy < (unsigned)IMGSZ && (unsigned)gx < (unsigned)IMGSZ) {
        size_t off = (size_t)gy * IMGSZ + gx;
        a  = *(const float4*)(img0 + off);
        bq = *(const float4*)(img1 + off);
    }
    uint4 d;
    d.x = __builtin_bit_cast(unsigned, __builtin_amdgcn_cvt_pkrtz(a.x, bq.x));
    d.y = __builtin_bit_cast(unsigned, __builtin_amdgcn_cvt_pkrtz(a.y, bq.y));
    d.z = __builtin_bit_cast(unsigned, __builtin_amdgcn_cvt_pkrtz(a.z, bq.z));
    d.w = __builtin_bit_cast(unsigned, __builtin_amdgcn_cvt_pkrtz(a.w, bq.w));
    *(uint4*)&padq[(size_t)idx * 4] = d;
}

// ---------- main kernel ----------------------------------------------------
__global__ __launch_bounds__(256) void fp_kernel(const unsigned* __restrict__ padq,
                                                 float* __restrict__ out) {
    __shared__ __align__(16) unsigned tileU[PITCH * MAXNY];   // 24600 B

    int blk = blockIdx.x;          // 5760 = VIEWS * 16
    int wc = blk & 15;
    int v = blk >> 4;

    int tid = threadIdx.x;
    int lane = tid & 63;
    int g = tid >> 6;                  // wave 0..3
    int lw = lane & 31;                // w within chunk
    int ph = (g << 1) | (lane >> 5);   // h phase 0..7
    int w = wc * WCHUNK + lw;

    double ang = -3.14159265358979323846 * (double)(v + 1) / (double)VIEWS
                 - 3.14159265358979323846;
    float c = (float)cos(ang);
    float s = (float)sin(ang);

    float xw = (float)w + 0.5f - 256.0f;
    float cxw = fmaf(c, xw, 255.5f);
    float sxw = fmaf(s, xw, 255.5f);

    // Per-thread valid-h interval (identical math to validated rounds 2-12).
    float lo = -1e30f, hi = 1e30f;
    {
        float coef = -s, base = cxw;
        if (fabsf(coef) > 1e-6f) {
            float a = (-1.0f - base) / coef;
            float bq = (512.0f - base) / coef;
            lo = fmaxf(lo, fminf(a, bq));
            hi = fminf(hi, fmaxf(a, bq));
        } else if (!(base > -1.0f && base < 512.0f)) {
            lo = 1e30f; hi = -1e30f;
        }
    }
    {
        float coef = c, base = sxw;
        if (fabsf(coef) > 1e-6f) {
            float a = (-1.0f - base) / coef;
            float bq = (512.0f - base) / coef;
            lo = fmaxf(lo, fminf(a, bq));
            hi = fminf(hi, fmaxf(a, bq));
        } else if (!(base > -1.0f && base < 512.0f)) {
            lo = 1e30f; hi = -1e30f;
        }
    }
    float h0f = fminf(fmaxf(floorf(lo + 255.5f) - 1.0f, 0.0f), 512.0f);
    float h1f = fminf(fmaxf(ceilf(hi + 255.5f) + 1.0f, -1.0f), 511.0f);
    int h0 = (int)h0f;
    int h1 = (int)h1f;

    // Block-uniform h range (each wave spans the full 32-w set -> identical).
    int bh0 = h0, bh1 = h1;
    #pragma unroll
    for (int m = 1; m < 64; m <<= 1) {
        bh0 = min(bh0, __shfl_xor(bh0, m, 64));
        bh1 = max(bh1, __shfl_xor(bh1, m, 64));
    }

    float xa = (float)(wc * WCHUNK) + 0.5f - 256.0f;
    float xb = xa + 31.0f;

    float acc0 = 0.0f, acc1 = 0.0f;
    float step8x = -8.0f * s;
    float step8y = 8.0f * c;

    for (int hc = bh0; hc <= bh1; hc += KH) {
        int hend = min(hc + KH - 1, bh1);

        float ha = (float)hc - 255.5f;
        float hb = (float)hend - 255.5f;
        float ix00 = c * xa - s * ha, ix01 = c * xa - s * hb;
        float ix10 = c * xb - s * ha, ix11 = c * xb - s * hb;
        float iy00 = s * xa + c * ha, iy01 = s * xa + c * hb;
        float iy10 = s * xb + c * ha, iy11 = s * xb + c * hb;
        float ixmn = fminf(fminf(ix00, ix01), fminf(ix10, ix11)) + 255.5f;
        float iymn = fminf(fminf(iy00, iy01), fminf(iy10, iy11)) + 255.5f;
        float iymx = fmaxf(fmaxf(iy00, iy01), fmaxf(iy10, iy11)) + 255.5f;
        int x_lo = (int)floorf(ixmn) - 1;
        int x_lo4 = x_lo & ~3;
        int y_lo = (int)floorf(iymn) - 1;
        int NY = min((int)floorf(iymx) + 3 - y_lo, MAXNY);
        int total4 = NY * NXF4;
        int nit = (total4 + 255) >> 8;     // <= 6

        __syncthreads();

        // Copy-only staging; uint4 global load -> two 8B LDS writes
        // (pitch 82 is even, so addresses are 8B-aligned).
        {
            const unsigned* pb = padq + (y_lo + PAD) * PW + (x_lo4 + PAD);
            for (int k = 0; k < nit; ++k) {
                int i = (k << 8) + tid;
                int ic = min(i, total4 - 1);
                int ry = ic / NXF4;                    // magic-mul (const 20)
                int rx4 = ic - ry * NXF4;
                uint4 val = *(const uint4*)(pb + 4 * ic + (PW - 4 * NXF4) * ry);
                int la = ry * PITCH + (rx4 << 2);
                *(uint2*)&tileU[la]     = make_uint2(val.x, val.y);
                *(uint2*)&tileU[la + 2] = make_uint2(val.z, val.w);
            }
        }
        __syncthreads();

        // Gather: phase ph handles h = hc+ph, +8, ... (<=8 iters).
        float hh0 = (float)(hc + ph) - 255.5f;
        float ixr = fmaf(-s, hh0, cxw) - (float)x_lo4;
        float iyr = fmaf(c, hh0, sxw) - (float)y_lo;
        h2 accp0 = (h2)0.0f;
        h2 accp1 = (h2)0.0f;
        int parity = 0;
        #pragma unroll 4
        for (int h = hc + ph; h <= hend; h += 8) {
            float fx = floorf(ixr);
            float fy = floorf(iyr);
            int lx = (int)fx;
            int ly = (int)fy;
            float wx1 = ixr - fx;
            float wy1 = iyr - fy;
            h2 wxs = __builtin_amdgcn_cvt_pkrtz(wx1, wx1);
            h2 wys = __builtin_amdgcn_cvt_pkrtz(wy1, wy1);
            const unsigned* p = tileU + (ly * PITCH + lx);
            h2 t00 = __builtin_bit_cast(h2, p[0]);
            h2 t01 = __builtin_bit_cast(h2, p[1]);
            h2 t10 = __builtin_bit_cast(h2, p[PITCH]);
            h2 t11 = __builtin_bit_cast(h2, p[PITCH + 1]);
            h2 r0 = t00 + (t01 - t00) * wxs;
            h2 r1 = t10 + (t11 - t10) * wxs;
            h2 contrib = r0 + (r1 - r0) * wys;
            if (parity) accp1 += contrib; else accp0 += contrib;
            parity ^= 1;
            ixr += step8x;
            iyr += step8y;
        }
        acc0 += (float)accp0.x + (float)accp1.x;
        acc1 += (float)accp0.y + (float)accp1.y;
    }

    // Reduce the 8 h-phase partials for both batches, reusing the tile.
    __syncthreads();
    tileU[(ph << 5) + lw] = __float_as_uint(acc0);
    tileU[256 + (ph << 5) + lw] = __float_as_uint(acc1);
    __syncthreads();
    if (tid < 64) {
        int lwr = tid & 31;
        int bsel = tid >> 5;           // 0 = batch0, 1 = batch1
        const unsigned* base = tileU + bsel * 256;
        float r = 0.0f;
        #pragma unroll
        for (int k = 0; k < 8; ++k)
            r += __uint_as_float(base[(k << 5) + lwr]);
        size_t o = (size_t)(wc * WCHUNK + lwr) * VIEWS + v;
        out[(size_t)bsel * IMGSZ * VIEWS + o] = r * 0.5f;
    }
}

extern "C" void kernel_launch(void* const* d_in, const int* in_sizes, int n_in,
                              void* d_out, int out_size, void* d_ws, size_t ws_size,
                              hipStream_t stream) {
    const float* x = (const float*)d_in[0];
    float* out = (float*)d_out;
    unsigned* padq = (unsigned*)d_ws;   // PH*PW*4 = 2,004,992 bytes

    constexpr int padTotal = PH * (PW / 4);          // 125312 groups
    pad_kernel<<<(padTotal + 255) / 256, 256, 0, stream>>>(x, padq);

    int nblocks = VIEWS * (IMGSZ / WCHUNK);          // 5760
    fp_kernel<<<nblocks, 256, 0, stream>>>(padq, out);
}

// Round 15
// 164.994 us; speedup vs baseline: 1.0236x; 1.0236x over previous
//
#include <hip/hip_runtime.h>

typedef __fp16 h2 __attribute__((ext_vector_type(2)));

constexpr int VIEWS = 360;
constexpr int IMGSZ = 512;
constexpr int WCHUNK = 64;   // w per block
constexpr int KH = 64;       // h per LDS chunk
constexpr int NXF4 = 25;     // staged box width in 4-dword groups (100 texels)
constexpr int PITCH = 101;   // LDS row pitch; >= staged width 100 (r14 bug:
                             // 97 < 100 -> row overlap). 101 mod 32 = 5 ->
                             // full 32-bank spread at |s|~1 (densest band).
constexpr int MAXNY = 94;    // max staged rows
constexpr int PW = 712;      // padded width (dword positions per row)
constexpr int PH = 704;      // padded height
constexpr int PAD = 96;

// ---------- pad kernel: zero-padded, BATCH-PACKED f16 texels ---------------
// padq[py][px] = (f16 img_b0[py-PAD][px-PAD], f16 img_b1[py-PAD][px-PAD])
__global__ __launch_bounds__(256) void pad_kernel(const float* __restrict__ x,
                                                  unsigned* __restrict__ padq) {
    constexpr int PW4 = PW / 4;              // 178 groups per row
    constexpr int total = PH * PW4;          // 125312 groups
    int idx = blockIdx.x * 256 + threadIdx.x;
    if (idx >= total) return;
    int py = idx / PW4;
    int px4 = idx - py * PW4;
    int gx = px4 * 4 - PAD;                  // multiple of 4
    int gy = py - PAD;
    const float* img0 = x;
    const float* img1 = x + (size_t)IMGSZ * IMGSZ;
    float4 a = make_float4(0.f, 0.f, 0.f, 0.f);
    float4 bq = a;
    if ((unsigned)gy < (unsigned)IMGSZ && (unsigned)gx < (unsigned)IMGSZ) {
        size_t off = (size_t)gy * IMGSZ + gx;    // gx%4==0 -> all-in/all-out
        a  = *(const float4*)(img0 + off);
        bq = *(const float4*)(img1 + off);
    }
    uint4 d;
    d.x = __builtin_bit_cast(unsigned, __builtin_amdgcn_cvt_pkrtz(a.x, bq.x));
    d.y = __builtin_bit_cast(unsigned, __builtin_amdgcn_cvt_pkrtz(a.y, bq.y));
    d.z = __builtin_bit_cast(unsigned, __builtin_amdgcn_cvt_pkrtz(a.z, bq.z));
    d.w = __builtin_bit_cast(unsigned, __builtin_amdgcn_cvt_pkrtz(a.w, bq.w));
    *(uint4*)&padq[(size_t)idx * 4] = d;
}

// ---------- main kernel: copy-only staging, packed-f16 lerp gather ---------
__global__ __launch_bounds__(256) void fp_kernel(const unsigned* __restrict__ padq,
                                                 float* __restrict__ out) {
    // 101 x 94 = 9494 dwords = 37976 B -> 4 blocks/CU.
    __shared__ __align__(16) unsigned tileU[PITCH * MAXNY];

    int blk = blockIdx.x;          // 2880 = VIEWS * 8
    int wc = blk & 7;
    int v = blk >> 3;

    int tid = threadIdx.x;
    int lane = tid & 63;
    int g = tid >> 6;              // h phase 0..3
    int w = wc * WCHUNK + lane;

    double ang = -3.14159265358979323846 * (double)(v + 1) / (double)VIEWS
                 - 3.14159265358979323846;
    float c = (float)cos(ang);
    float s = (float)sin(ang);

    float xw = (float)w + 0.5f - 256.0f;
    float cxw = fmaf(c, xw, 255.5f);
    float sxw = fmaf(s, xw, 255.5f);

    // Per-thread valid-h interval (identical to validated rounds 2-13).
    float lo = -1e30f, hi = 1e30f;
    {
        float coef = -s, base = cxw;
        if (fabsf(coef) > 1e-6f) {
            float a = (-1.0f - base) / coef;
            float bq = (512.0f - base) / coef;
            lo = fmaxf(lo, fminf(a, bq));
            hi = fminf(hi, fmaxf(a, bq));
        } else if (!(base > -1.0f && base < 512.0f)) {
            lo = 1e30f; hi = -1e30f;
        }
    }
    {
        float coef = c, base = sxw;
        if (fabsf(coef) > 1e-6f) {
            float a = (-1.0f - base) / coef;
            float bq = (512.0f - base) / coef;
            lo = fmaxf(lo, fminf(a, bq));
            hi = fminf(hi, fmaxf(a, bq));
        } else if (!(base > -1.0f && base < 512.0f)) {
            lo = 1e30f; hi = -1e30f;
        }
    }
    float h0f = fminf(fmaxf(floorf(lo + 255.5f) - 1.0f, 0.0f), 512.0f);
    float h1f = fminf(fmaxf(ceilf(hi + 255.5f) + 1.0f, -1.0f), 511.0f);
    int h0 = (int)h0f;
    int h1 = (int)h1f;

    int bh0 = h0, bh1 = h1;
    #pragma unroll
    for (int m = 1; m < 64; m <<= 1) {
        bh0 = min(bh0, __shfl_xor(bh0, m, 64));
        bh1 = max(bh1, __shfl_xor(bh1, m, 64));
    }

    float xa = (float)(wc * WCHUNK) + 0.5f - 256.0f;
    float xb = xa + 63.0f;

    float acc0 = 0.0f, acc1 = 0.0f;
    float step4x = -4.0f * s;
    float step4y = 4.0f * c;

    for (int hc = bh0; hc <= bh1; hc += KH) {
        int hend = min(hc + KH - 1, bh1);

        float ha = (float)hc - 255.5f;
        float hb = (float)hend - 255.5f;
        float ix00 = c * xa - s * ha, ix01 = c * xa - s * hb;
        float ix10 = c * xb - s * ha, ix11 = c * xb - s * hb;
        float iy00 = s * xa + c * ha, iy01 = s * xa + c * hb;
        float iy10 = s * xb + c * ha, iy11 = s * xb + c * hb;
        float ixmn = fminf(fminf(ix00, ix01), fminf(ix10, ix11)) + 255.5f;
        float iymn = fminf(fminf(iy00, iy01), fminf(iy10, iy11)) + 255.5f;
        float iymx = fmaxf(fmaxf(iy00, iy01), fmaxf(iy10, iy11)) + 255.5f;
        int x_lo = (int)floorf(ixmn) - 1;
        int x_lo4 = x_lo & ~3;
        int y_lo = (int)floorf(iymn) - 1;
        int NY = min((int)floorf(iymx) + 3 - y_lo, MAXNY);
        int total4 = NY * NXF4;
        int nit = (total4 + 255) >> 8;     // <= 10

        __syncthreads();

        // Copy-only staging of batch-packed texels; clamped slot index for
        // both load and store. Odd pitch -> store the uint4 as scalar dwords
        // (compiler merges to ds_write2_b32 pairs).
        {
            const unsigned* pb = padq + (y_lo + PAD) * PW + (x_lo4 + PAD);
            for (int k = 0; k < nit; ++k) {
                int i = (k << 8) + tid;
                int ic = min(i, total4 - 1);
                int ry = ic / NXF4;                    // magic-mul (const 25)
                int rx4 = ic - ry * NXF4;
                uint4 val = *(const uint4*)(pb + 4 * ic + (PW - 4 * NXF4) * ry);
                int la = ry * PITCH + (rx4 << 2);
                tileU[la]     = val.x;
                tileU[la + 1] = val.y;
                tileU[la + 2] = val.z;
                tileU[la + 3] = val.w;
            }
        }
        __syncthreads();

        // Gather: 2 x ds_read2_b32 per sample (const offsets 0,1 / 101,102);
        // packed-f16 lerp serves both batches. Wave g: h = hc+g, +4, ...
        float hh0 = (float)(hc + g) - 255.5f;
        float ixr = fmaf(-s, hh0, cxw) - (float)x_lo4;
        float iyr = fmaf(c, hh0, sxw) - (float)y_lo;
        h2 accp0 = (h2)0.0f;
        h2 accp1 = (h2)0.0f;
        int parity = 0;
        #pragma unroll 4
        for (int h = hc + g; h <= hend; h += 4) {
            float fx = floorf(ixr);
            float fy = floorf(iyr);
            int lx = (int)fx;
            int ly = (int)fy;
            float wx1 = ixr - fx;
            float wy1 = iyr - fy;
            h2 wxs = __builtin_amdgcn_cvt_pkrtz(wx1, wx1);
            h2 wys = __builtin_amdgcn_cvt_pkrtz(wy1, wy1);
            const unsigned* p = tileU + (ly * PITCH + lx);
            h2 t00 = __builtin_bit_cast(h2, p[0]);
            h2 t01 = __builtin_bit_cast(h2, p[1]);
            h2 t10 = __builtin_bit_cast(h2, p[PITCH]);
            h2 t11 = __builtin_bit_cast(h2, p[PITCH + 1]);
            h2 r0 = t00 + (t01 - t00) * wxs;
            h2 r1 = t10 + (t11 - t10) * wxs;
            h2 contrib = r0 + (r1 - r0) * wys;
            if (parity) accp1 += contrib; else accp0 += contrib;
            parity ^= 1;
            ixr += step4x;
            iyr += step4y;
        }
        acc0 += (float)accp0.x + (float)accp1.x;
        acc1 += (float)accp0.y + (float)accp1.y;
    }

    // Reduce the 4 h-phase partials for both batches, reusing the tile.
    __syncthreads();
    tileU[(g << 6) + lane] = __float_as_uint(acc0);
    tileU[256 + (g << 6) + lane] = __float_as_uint(acc1);
    __syncthreads();
    if (g == 0) {
        float r0 = __uint_as_float(tileU[lane]) + __uint_as_float(tileU[64 + lane]) +
                   __uint_as_float(tileU[128 + lane]) + __uint_as_float(tileU[192 + lane]);
        float r1 = __uint_as_float(tileU[256 + lane]) + __uint_as_float(tileU[320 + lane]) +
                   __uint_as_float(tileU[384 + lane]) + __uint_as_float(tileU[448 + lane]);
        size_t o = (size_t)w * VIEWS + v;
        out[o] = r0 * 0.5f;
        out[(size_t)IMGSZ * VIEWS + o] = r1 * 0.5f;
    }
}

extern "C" void kernel_launch(void* const* d_in, const int* in_sizes, int n_in,
                              void* d_out, int out_size, void* d_ws, size_t ws_size,
                              hipStream_t stream) {
    const float* x = (const float*)d_in[0];
    float* out = (float*)d_out;
    unsigned* padq = (unsigned*)d_ws;   // PH*PW*4 = 2,004,992 bytes

    constexpr int padTotal = PH * (PW / 4);          // 125312 groups
    pad_kernel<<<(padTotal + 255) / 256, 256, 0, stream>>>(x, padq);

    int nblocks = VIEWS * (IMGSZ / WCHUNK);          // 2880
    fp_kernel<<<nblocks, 256, 0, stream>>>(padq, out);
}

// Round 16
// 159.313 us; speedup vs baseline: 1.0601x; 1.0357x over previous
//
#include <hip/hip_runtime.h>

typedef __fp16 h2 __attribute__((ext_vector_type(2)));

constexpr int VIEWS = 360;
constexpr int IMGSZ = 512;
constexpr int WCHUNK = 64;   // w per block
constexpr int KH = 64;       // h per LDS chunk
constexpr int NXF4 = 25;     // staged box width in 4-dword groups (100 texels)
constexpr int PITCH = 100;   // LDS row pitch == staged width (b128 staging!)
constexpr int MAXNY = 94;    // max staged rows
constexpr int PW = 712;      // padq width (dwords per row), 704 rows
constexpr int PH = 704;
constexpr int PWT = 704;     // padT width (dwords per row), 704 rows
constexpr int PAD = 96;
constexpr size_t PADQ_DW = (size_t)PH * PW;    // 501,248 dwords

// ---------- pad kernel: batch-packed f16 texels, row-major AND transposed --
// padq[py][px] = pack(b0[y][x], b1[y][x]),  y=py-PAD, x=px-PAD
// padT[px][py] = same value (transposed), px < 704
__global__ __launch_bounds__(256) void pad_kernel(const float* __restrict__ x,
                                                  unsigned* __restrict__ padq,
                                                  unsigned* __restrict__ padT) {
    constexpr int PW4 = PW / 4;              // 178 groups per row
    constexpr int total = PH * PW4;          // 125312 groups
    int idx = blockIdx.x * 256 + threadIdx.x;
    if (idx >= total) return;
    int py = idx / PW4;
    int px4 = idx - py * PW4;
    int gx = px4 * 4 - PAD;                  // multiple of 4
    int gy = py - PAD;
    const float* img0 = x;
    const float* img1 = x + (size_t)IMGSZ * IMGSZ;
    float4 a = make_float4(0.f, 0.f, 0.f, 0.f);
    float4 bq = a;
    if ((unsigned)gy < (unsigned)IMGSZ && (unsigned)gx < (unsigned)IMGSZ) {
        size_t off = (size_t)gy * IMGSZ + gx;    // gx%4==0 -> all-in/all-out
        a  = *(const float4*)(img0 + off);
        bq = *(const float4*)(img1 + off);
    }
    uint4 d;
    d.x = __builtin_bit_cast(unsigned, __builtin_amdgcn_cvt_pkrtz(a.x, bq.x));
    d.y = __builtin_bit_cast(unsigned, __builtin_amdgcn_cvt_pkrtz(a.y, bq.y));
    d.z = __builtin_bit_cast(unsigned, __builtin_amdgcn_cvt_pkrtz(a.z, bq.z));
    d.w = __builtin_bit_cast(unsigned, __builtin_amdgcn_cvt_pkrtz(a.w, bq.w));
    *(uint4*)&padq[(size_t)idx * 4] = d;
    // transposed copy (scattered 4B stores; 2 MB one-pass, L2-absorbed)
    unsigned dd[4] = {d.x, d.y, d.z, d.w};
    int px = px4 * 4;
    #pragma unroll
    for (int j = 0; j < 4; ++j)
        if (px + j < PWT) padT[(size_t)(px + j) * PWT + py] = dd[j];
}

// ---------- main kernel: per-view layout A/B, generic (u,t) path -----------
__global__ __launch_bounds__(256) void fp_kernel(const unsigned* __restrict__ padq,
                                                 const unsigned* __restrict__ padT,
                                                 float* __restrict__ out) {
    __shared__ __align__(16) unsigned tileU[PITCH * MAXNY];   // 37600 B

    int blk = blockIdx.x;          // 2880 = VIEWS * 8
    int wc = blk & 7;
    int v = blk >> 3;

    int tid = threadIdx.x;
    int lane = tid & 63;
    int g = tid >> 6;              // h phase 0..3
    int w = wc * WCHUNK + lane;

    double ang = -3.14159265358979323846 * (double)(v + 1) / (double)VIEWS
                 - 3.14159265358979323846;
    float c = (float)cos(ang);
    float s = (float)sin(ang);

    // Layout select: gather lane-stride = P*(dt/dw) + (du/dw).
    // A (row-major):  stride = 100*s + c  -> good when |s| small
    // B (transposed): stride = 100*c + s  -> good when |c| small
    bool useB = fabsf(s) > fabsf(c);
    float uc = useB ? s : c;        // u = uc*xw + us*hh + 255.5 (contiguous axis)
    float us = useB ? c : -s;
    float tc = useB ? c : s;        // t = tc*xw + ts*hh + 255.5 (row axis)
    float ts = useB ? -s : c;
    const unsigned* basePad = useB ? padT : padq;
    int PWsel = useB ? PWT : PW;

    float xw = (float)w + 0.5f - 256.0f;
    float cu = fmaf(uc, xw, 255.5f);
    float ct = fmaf(tc, xw, 255.5f);

    // Per-thread valid-h interval (same math as validated rounds; the
    // (u,t) pair is just a permutation of (ix,iy), validity is symmetric).
    float lo = -1e30f, hi = 1e30f;
    {
        float coef = us, base = cu;
        if (fabsf(coef) > 1e-6f) {
            float a = (-1.0f - base) / coef;
            float bq = (512.0f - base) / coef;
            lo = fmaxf(lo, fminf(a, bq));
            hi = fminf(hi, fmaxf(a, bq));
        } else if (!(base > -1.0f && base < 512.0f)) {
            lo = 1e30f; hi = -1e30f;
        }
    }
    {
        float coef = ts, base = ct;
        if (fabsf(coef) > 1e-6f) {
            float a = (-1.0f - base) / coef;
            float bq = (512.0f - base) / coef;
            lo = fmaxf(lo, fminf(a, bq));
            hi = fminf(hi, fmaxf(a, bq));
        } else if (!(base > -1.0f && base < 512.0f)) {
            lo = 1e30f; hi = -1e30f;
        }
    }
    float h0f = fminf(fmaxf(floorf(lo + 255.5f) - 1.0f, 0.0f), 512.0f);
    float h1f = fminf(fmaxf(ceilf(hi + 255.5f) + 1.0f, -1.0f), 511.0f);
    int h0 = (int)h0f;
    int h1 = (int)h1f;

    int bh0 = h0, bh1 = h1;
    #pragma unroll
    for (int m = 1; m < 64; m <<= 1) {
        bh0 = min(bh0, __shfl_xor(bh0, m, 64));
        bh1 = max(bh1, __shfl_xor(bh1, m, 64));
    }

    float xa = (float)(wc * WCHUNK) + 0.5f - 256.0f;
    float xb = xa + 63.0f;

    float acc0 = 0.0f, acc1 = 0.0f;
    float step4u = 4.0f * us;
    float step4t = 4.0f * ts;

    for (int hc = bh0; hc <= bh1; hc += KH) {
        int hend = min(hc + KH - 1, bh1);

        float ha = (float)hc - 255.5f;
        float hb = (float)hend - 255.5f;
        float u00 = uc * xa + us * ha, u01 = uc * xa + us * hb;
        float u10 = uc * xb + us * ha, u11 = uc * xb + us * hb;
        float t00c = tc * xa + ts * ha, t01c = tc * xa + ts * hb;
        float t10c = tc * xb + ts * ha, t11c = tc * xb + ts * hb;
        float umn = fminf(fminf(u00, u01), fminf(u10, u11)) + 255.5f;
        float tmn = fminf(fminf(t00c, t01c), fminf(t10c, t11c)) + 255.5f;
        float tmx = fmaxf(fmaxf(t00c, t01c), fmaxf(t10c, t11c)) + 255.5f;
        int u_lo = (int)floorf(umn) - 1;
        int u_lo4 = u_lo & ~3;
        int t_lo = (int)floorf(tmn) - 1;
        int NY = min((int)floorf(tmx) + 3 - t_lo, MAXNY);
        int total4 = NY * NXF4;
        int nit = (total4 + 255) >> 8;     // <= 10

        __syncthreads();

        // Copy-only b128 staging (lane-contiguous -> conflict-free writes),
        // identical to r12; source selected per view (padq rows / padT rows).
        {
            const unsigned* pb = basePad + (t_lo + PAD) * PWsel + (u_lo4 + PAD);
            for (int k = 0; k < nit; ++k) {
                int i = (k << 8) + tid;
                int ic = min(i, total4 - 1);
                int ry = ic / NXF4;                    // magic-mul (const 25)
                uint4 val = *(const uint4*)(pb + 4 * ic + (PWsel - 4 * NXF4) * ry);
                *(uint4*)&tileU[ic << 2] = val;
            }
        }
        __syncthreads();

        // Gather: 2 x ds_read2_b32 (offsets 0,1 / 100,101); packed-f16
        // bilinear (lerp wu along contiguous axis, wt across rows).
        float hh0 = (float)(hc + g) - 255.5f;
        float ur = fmaf(us, hh0, cu) - (float)u_lo4;
        float tr = fmaf(ts, hh0, ct) - (float)t_lo;
        h2 accp0 = (h2)0.0f;
        h2 accp1 = (h2)0.0f;
        int parity = 0;
        #pragma unroll 4
        for (int h = hc + g; h <= hend; h += 4) {
            float fu = floorf(ur);
            float ft = floorf(tr);
            int lu = (int)fu;
            int lt = (int)ft;
            float wu1 = ur - fu;
            float wt1 = tr - ft;
            h2 wus = __builtin_amdgcn_cvt_pkrtz(wu1, wu1);
            h2 wts = __builtin_amdgcn_cvt_pkrtz(wt1, wt1);
            const unsigned* p = tileU + (lt * PITCH + lu);
            h2 t00 = __builtin_bit_cast(h2, p[0]);
            h2 t01 = __builtin_bit_cast(h2, p[1]);
            h2 t10 = __builtin_bit_cast(h2, p[PITCH]);
            h2 t11 = __builtin_bit_cast(h2, p[PITCH + 1]);
            h2 r0 = t00 + (t01 - t00) * wus;
            h2 r1 = t10 + (t11 - t10) * wus;
            h2 contrib = r0 + (r1 - r0) * wts;
            if (parity) accp1 += contrib; else accp0 += contrib;
            parity ^= 1;
            ur += step4u;
            tr += step4t;
        }
        acc0 += (float)accp0.x + (float)accp1.x;
        acc1 += (float)accp0.y + (float)accp1.y;
    }

    // Reduce the 4 h-phase partials for both batches, reusing the tile.
    __syncthreads();
    tileU[(g << 6) + lane] = __float_as_uint(acc0);
    tileU[256 + (g << 6) + lane] = __float_as_uint(acc1);
    __syncthreads();
    if (g == 0) {
        float r0 = __uint_as_float(tileU[lane]) + __uint_as_float(tileU[64 + lane]) +
                   __uint_as_float(tileU[128 + lane]) + __uint_as_float(tileU[192 + lane]);
        float r1 = __uint_as_float(tileU[256 + lane]) + __uint_as_float(tileU[320 + lane]) +
                   __uint_as_float(tileU[384 + lane]) + __uint_as_float(tileU[448 + lane]);
        size_t o = (size_t)w * VIEWS + v;
        out[o] = r0 * 0.5f;
        out[(size_t)IMGSZ * VIEWS + o] = r1 * 0.5f;
    }
}

extern "C" void kernel_launch(void* const* d_in, const int* in_sizes, int n_in,
                              void* d_out, int out_size, void* d_ws, size_t ws_size,
                              hipStream_t stream) {
    const float* x = (const float*)d_in[0];
    float* out = (float*)d_out;
    unsigned* padq = (unsigned*)d_ws;                 // 2,004,992 B
    unsigned* padT = padq + PADQ_DW;                  // 1,982,464 B (3.99 MB total)

    constexpr int padTotal = PH * (PW / 4);           // 125312 groups
    pad_kernel<<<(padTotal + 255) / 256, 256, 0, stream>>>(x, padq, padT);

    int nblocks = VIEWS * (IMGSZ / WCHUNK);           // 2880
    fp_kernel<<<nblocks, 256, 0, stream>>>(padq, padT, out);
}